// Round 1
// baseline (343.326 us; speedup 1.0000x reference)
//
#include <hip/hip_runtime.h>

// Problem constants
#define NIMG 32
#define H 112
#define W 112
#define CI 64
#define CO 128
// K = 3*3*64 = 576, K-steps of 32 -> 18 steps

typedef __attribute__((ext_vector_type(8))) __bf16 bf16x8;
typedef __attribute__((ext_vector_type(4))) float f32x4;
typedef __attribute__((ext_vector_type(4))) short short4v;

// Quantize to 8-bit fixed point, but return the INTEGER value (-128..127)
// encoded as bf16 bits (exact: |int| <= 128 fits bf16's 8-bit significand).
__device__ __forceinline__ short q8bits(float v) {
    float t = rintf(v * 128.0f);              // v_rndne: round-half-even == np.round
    t = fminf(fmaxf(t, -128.0f), 127.0f);     // clip to [-1, 1-2^-7] in integer domain
    union { float f; unsigned u; } cv; cv.f = t;
    return (short)(cv.u >> 16);               // exact fp32->bf16 truncation (int-valued)
}

// Weights HWIO [3][3][64][128] fp32 -> quantized ints packed in MFMA B-fragment order.
// B-frag layout for mfma_f32_16x16x32_bf16: lane holds B[k=(lane>>4)*8+j][n=lane&15].
// Packed: bp[(((kt*8 + nt)*64 + lane)*8) + j], kt=k/32 (18), nt=n/16 (8).
__global__ __launch_bounds__(256) void quant_pack_w(const float* __restrict__ w,
                                                    short* __restrict__ bp) {
    int idx = blockIdx.x * 256 + threadIdx.x;   // 0..73727 (grid sized exactly)
    int j    = idx & 7;
    int lane = (idx >> 3) & 63;
    int nt   = (idx >> 9) & 7;
    int kt   = idx >> 12;
    int k = kt * 32 + (lane >> 4) * 8 + j;      // 0..575  == (r*3+s)*64 + ci (HWIO flat)
    int n = nt * 16 + (lane & 15);              // co
    bp[idx] = q8bits(w[k * CO + n]);
}

#define LDSW 114        // 112 + 2 halo cols
#define LDST 72         // CI=64 padded to 72 (stride 144B -> low LDS bank conflict)

__global__ __launch_bounds__(256, 3) void conv_kernel(const float* __restrict__ x,
                                                      const short* __restrict__ bp,
                                                      float* __restrict__ out) {
    __shared__ short xs[3 * LDSW * LDST];       // 49248 B: 3 input rows x 114 cols x 64ci (bf16 ints)

    int bid = blockIdx.x;
    int n = bid / H;
    int h = bid - n * H;
    int tid = threadIdx.x;

    // ---- Stage input halo: fp32 global -> quantize -> bf16(int) LDS ----
    const float* xin = x + (size_t)n * (H * W * CI);
    for (int r = 0; r < 3; ++r) {
        int hr = h + r - 1;
        bool rowok = ((unsigned)hr < (unsigned)H);
        const float* srow = xin + (size_t)hr * (W * CI);
        for (int t = tid; t < LDSW * 16; t += 256) {   // 16 float4 per col
            int c = t >> 4;
            int ci4 = (t & 15) << 2;
            int wcol = c - 1;
            float4 v = {0.0f, 0.0f, 0.0f, 0.0f};
            if (rowok && (unsigned)wcol < (unsigned)W) {
                v = *(const float4*)&srow[wcol * CI + ci4];
            }
            short4v sv;
            sv.x = q8bits(v.x); sv.y = q8bits(v.y);
            sv.z = q8bits(v.z); sv.w = q8bits(v.w);
            *(short4v*)&xs[(r * LDSW + c) * LDST + ci4] = sv;
        }
    }
    __syncthreads();

    // ---- Implicit GEMM: M=112 (w), N=128 (co), K=576; wave owns 32 co ----
    int lane = tid & 63;
    int wave = tid >> 6;
    int laneoff = (lane & 15) * LDST + (lane >> 4) * 8;  // A: m=lane&15, k=(lane>>4)*8+j

    const bf16x8* bfr = (const bf16x8*)bp;
    int nt0 = wave * 2;

    f32x4 acc[7][2];
    #pragma unroll
    for (int mt = 0; mt < 7; ++mt) {
        acc[mt][0] = (f32x4){0.f, 0.f, 0.f, 0.f};
        acc[mt][1] = (f32x4){0.f, 0.f, 0.f, 0.f};
    }

    #pragma unroll
    for (int kk = 0; kk < 18; ++kk) {
        int rs = kk >> 1;            // (r,s) block of 64 k's; step covers 32
        int r = rs / 3;
        int s = rs - r * 3;
        bf16x8 b0 = bfr[(kk * 8 + nt0    ) * 64 + lane];
        bf16x8 b1 = bfr[(kk * 8 + nt0 + 1) * 64 + lane];
        int abase = (r * LDSW + s) * LDST + (kk & 1) * 32 + laneoff;
        #pragma unroll
        for (int mt = 0; mt < 7; ++mt) {
            bf16x8 a = *(const bf16x8*)&xs[abase + mt * 16 * LDST];
            acc[mt][0] = __builtin_amdgcn_mfma_f32_16x16x32_bf16(a, b0, acc[mt][0], 0, 0, 0);
            acc[mt][1] = __builtin_amdgcn_mfma_f32_16x16x32_bf16(a, b1, acc[mt][1], 0, 0, 0);
        }
    }

    // ---- Epilogue: out = floor(S/128)/128 (exact) ----
    // D layout: row=(lane>>4)*4+reg (m within tile), col=lane&15 (n within tile)
    float* orow = out + (size_t)(n * H + h) * (W * CO);
    int colc = wave * 32 + (lane & 15);
    int rowb = (lane >> 4) * 4;
    #pragma unroll
    for (int mt = 0; mt < 7; ++mt) {
        #pragma unroll
        for (int t2 = 0; t2 < 2; ++t2) {
            int co = colc + t2 * 16;
            #pragma unroll
            for (int rg = 0; rg < 4; ++rg) {
                int m = mt * 16 + rowb + rg;
                float sv = acc[mt][t2][rg];
                orow[m * CO + co] = floorf(sv * 0.0078125f) * 0.0078125f;
            }
        }
    }
}

extern "C" void kernel_launch(void* const* d_in, const int* in_sizes, int n_in,
                              void* d_out, int out_size, void* d_ws, size_t ws_size,
                              hipStream_t stream) {
    const float* x = (const float*)d_in[0];     // (32,112,112,64) fp32 NHWC
    const float* w = (const float*)d_in[1];     // (3,3,64,128) fp32 HWIO
    float* out = (float*)d_out;                 // (32,112,112,128) fp32
    short* bp = (short*)d_ws;                   // 576*128 bf16 = 147456 B packed weights

    quant_pack_w<<<288, 256, 0, stream>>>(w, bp);            // 288*256 == 73728 exactly
    conv_kernel<<<NIMG * H, 256, 0, stream>>>(x, bp, out);   // 3584 blocks
}

// Round 2
// 333.315 us; speedup vs baseline: 1.0300x; 1.0300x over previous
//
#include <hip/hip_runtime.h>

// Problem constants
#define NIMG 32
#define H 112
#define W 112
#define CI 64
#define CO 128
// K = 3*3*64 = 576 -> 18 K-steps of 32

typedef __attribute__((ext_vector_type(8))) __bf16 bf16x8;
typedef __attribute__((ext_vector_type(4))) float f32x4;
typedef __attribute__((ext_vector_type(4))) short short4v;
typedef __attribute__((ext_vector_type(4))) int int4v;

// Quantize to 8-bit fixed point; return INTEGER value (-128..127) as bf16 bits.
// Exact: ints of magnitude <=128 are exactly representable in bf16.
__device__ __forceinline__ short q8bits(float v) {
    float t = rintf(v * 128.0f);              // round-half-even == np.round
    t = fminf(fmaxf(t, -128.0f), 127.0f);
    union { float f; unsigned u; } cv; cv.f = t;
    return (short)(cv.u >> 16);               // exact fp32->bf16 (int-valued)
}

// Weights HWIO [576][128] fp32 -> MFMA B-frag order (verified exact in R1).
// bp[(((kk*8 + nt)*64 + lane)*8) + j] = q(w[(kk*32 + (lane>>4)*8 + j)*128 + nt*16 + (lane&15)])
__global__ __launch_bounds__(256) void quant_pack_w(const float* __restrict__ w,
                                                    short* __restrict__ bp) {
    int idx = blockIdx.x * 256 + threadIdx.x;   // grid sized exactly 73728
    int j    = idx & 7;
    int lane = (idx >> 3) & 63;
    int nt   = (idx >> 9) & 7;
    int kt   = idx >> 12;
    int k = kt * 32 + (lane >> 4) * 8 + j;
    int n = nt * 16 + (lane & 15);
    bp[idx] = q8bits(w[k * CO + n]);
}

// Activation prepass: fp32 NHWC -> bf16-int NHWC (same layout), 8 elems/thread.
__global__ __launch_bounds__(256) void quant_x(const float* __restrict__ x,
                                               short* __restrict__ xq) {
    size_t i = ((size_t)blockIdx.x * 256 + threadIdx.x) * 8;
    float4 v0 = *(const float4*)&x[i];
    float4 v1 = *(const float4*)&x[i + 4];
    short4v a, b;
    a.x = q8bits(v0.x); a.y = q8bits(v0.y); a.z = q8bits(v0.z); a.w = q8bits(v0.w);
    b.x = q8bits(v1.x); b.y = q8bits(v1.y); b.z = q8bits(v1.z); b.w = q8bits(v1.w);
    *(short4v*)&xq[i]     = a;
    *(short4v*)&xq[i + 4] = b;
}

// ---------------- Main conv: 2 output rows per block, 4 waves ----------------
// Wave w: row_sel = w>>1 (output row h0+row_sel), co half = (w&1)*64.
// LDS: 4 input rows x 114 cols x 64ci bf16, XOR-swizzled chunks:
//   phys addr (shorts) = row*LROW + c*64 + ((chunk_log ^ (c&7)) * 8)
// DMA writes lane l -> base + l*16B (c = 1+i*8+(l>>3), chunk_phys = l&7),
// so lane l sources global chunk (l&7)^(c&7) -> swizzle for free, coalesced.
#define LROW 7296   // 114*64 shorts = 14592 B per row slot

__global__ __launch_bounds__(256, 2) void conv2(const short* __restrict__ xq,
                                                const short* __restrict__ bp,
                                                float* __restrict__ out) {
    __shared__ short xs[4 * LROW];              // 58368 B -> 2 blocks/CU
    int bid = blockIdx.x;
    int n  = bid / 56;
    int hp = bid - n * 56;
    int h0 = hp * 2;
    int tid  = threadIdx.x;
    int lane = tid & 63;
    int wave = tid >> 6;

    // ---- stage: each wave DMAs one input row (14 x 1KB chunks) ----
    short* ldsrow = &xs[wave * LROW];
    int hr = h0 - 1 + wave;
    if ((unsigned)hr < (unsigned)H) {
        const short* grow = xq + ((size_t)(n * H + hr) * W) * CI;
        int lc = lane >> 3;                     // local col within 8-col chunk group
        int jp = lane & 7;                      // physical 16B chunk within col
        #pragma unroll
        for (int i = 0; i < 14; ++i) {
            int gc = i * 8 + lc;                // global col 0..111
            int jl = jp ^ ((gc + 1) & 7);       // logical chunk to fetch
            const short* g = grow + gc * 64 + jl * 8;
            __builtin_amdgcn_global_load_lds(
                (const __attribute__((address_space(1))) void*)g,
                (__attribute__((address_space(3))) void*)(ldsrow + 64 + i * 512),
                16, 0, 0);
        }
    } else {
        for (int t = lane; t < 912; t += 64)    // zero whole row (boundary blocks)
            *(int4v*)&ldsrow[t * 8] = (int4v){0, 0, 0, 0};
    }
    if (lane < 16) {                            // zero halo cols c=0 and c=113
        int c = (lane & 8) ? 113 : 0;
        *(int4v*)&ldsrow[c * 64 + (lane & 7) * 8] = (int4v){0, 0, 0, 0};
    }
    __syncthreads();

    // ---- implicit GEMM: wave = 112 m x 64 co, K=576 ----
    int lane15  = lane & 15;
    int hi      = lane >> 4;                    // 0..3
    int row_sel = wave >> 1;
    int nt0     = (wave & 1) * 4;               // first of 4 n-tiles

    const bf16x8* bfr = (const bf16x8*)bp;

    f32x4 acc[7][4];
    #pragma unroll
    for (int mt = 0; mt < 7; ++mt)
        #pragma unroll
        for (int t = 0; t < 4; ++t)
            acc[mt][t] = (f32x4){0.f, 0.f, 0.f, 0.f};

    #pragma unroll
    for (int r = 0; r < 3; ++r) {
        int rbase = (row_sel + r) * LROW;
        #pragma unroll
        for (int s = 0; s < 3; ++s) {
            int cb = s + lane15;                // LDS col for m = lane15 (mt adds 16)
            int sx = cb & 7;                    // swizzle key (mt*16 ≡ 0 mod 8)
            int abase = rbase + cb * 64;
            #pragma unroll
            for (int kh = 0; kh < 2; ++kh) {
                int kk = (r * 3 + s) * 2 + kh;
                bf16x8 b0 = bfr[(kk * 8 + nt0    ) * 64 + lane];
                bf16x8 b1 = bfr[(kk * 8 + nt0 + 1) * 64 + lane];
                bf16x8 b2 = bfr[(kk * 8 + nt0 + 2) * 64 + lane];
                bf16x8 b3 = bfr[(kk * 8 + nt0 + 3) * 64 + lane];
                int joff = ((kh * 4 + hi) ^ sx) * 8;
                #pragma unroll
                for (int mt = 0; mt < 7; ++mt) {
                    bf16x8 a = *(const bf16x8*)&xs[abase + mt * 1024 + joff];
                    acc[mt][0] = __builtin_amdgcn_mfma_f32_16x16x32_bf16(a, b0, acc[mt][0], 0, 0, 0);
                    acc[mt][1] = __builtin_amdgcn_mfma_f32_16x16x32_bf16(a, b1, acc[mt][1], 0, 0, 0);
                    acc[mt][2] = __builtin_amdgcn_mfma_f32_16x16x32_bf16(a, b2, acc[mt][2], 0, 0, 0);
                    acc[mt][3] = __builtin_amdgcn_mfma_f32_16x16x32_bf16(a, b3, acc[mt][3], 0, 0, 0);
                }
            }
        }
    }

    // ---- epilogue: out = floor(S/128)/128 (exact) ----
    float* orow = out + (size_t)((n * H + h0 + row_sel) * W) * CO;
    int co0  = (wave & 1) * 64 + lane15;
    int rowb = hi * 4;
    #pragma unroll
    for (int mt = 0; mt < 7; ++mt)
        #pragma unroll
        for (int t = 0; t < 4; ++t)
            #pragma unroll
            for (int rg = 0; rg < 4; ++rg) {
                int m = mt * 16 + rowb + rg;
                orow[m * CO + co0 + t * 16] =
                    floorf(acc[mt][t][rg] * 0.0078125f) * 0.0078125f;
            }
}

// ---------------- R1 fallback (ws too small for xq): verified exact ----------------
#define LDSW 114
#define LDST 72
__global__ __launch_bounds__(256, 3) void conv_fb(const float* __restrict__ x,
                                                  const short* __restrict__ bp,
                                                  float* __restrict__ out) {
    __shared__ short xs[3 * LDSW * LDST];
    int bid = blockIdx.x;
    int n = bid / H;
    int h = bid - n * H;
    int tid = threadIdx.x;
    const float* xin = x + (size_t)n * (H * W * CI);
    for (int r = 0; r < 3; ++r) {
        int hrow = h + r - 1;
        bool rowok = ((unsigned)hrow < (unsigned)H);
        const float* srow = xin + (size_t)hrow * (W * CI);
        for (int t = tid; t < LDSW * 16; t += 256) {
            int c = t >> 4;
            int ci4 = (t & 15) << 2;
            int wcol = c - 1;
            float4 v = {0.f, 0.f, 0.f, 0.f};
            if (rowok && (unsigned)wcol < (unsigned)W)
                v = *(const float4*)&srow[wcol * CI + ci4];
            short4v sv;
            sv.x = q8bits(v.x); sv.y = q8bits(v.y);
            sv.z = q8bits(v.z); sv.w = q8bits(v.w);
            *(short4v*)&xs[(r * LDSW + c) * LDST + ci4] = sv;
        }
    }
    __syncthreads();
    int lane = tid & 63;
    int wave = tid >> 6;
    int laneoff = (lane & 15) * LDST + (lane >> 4) * 8;
    const bf16x8* bfr = (const bf16x8*)bp;
    int nt0 = wave * 2;
    f32x4 acc[7][2];
    #pragma unroll
    for (int mt = 0; mt < 7; ++mt) {
        acc[mt][0] = (f32x4){0.f, 0.f, 0.f, 0.f};
        acc[mt][1] = (f32x4){0.f, 0.f, 0.f, 0.f};
    }
    #pragma unroll
    for (int kk = 0; kk < 18; ++kk) {
        int rs = kk >> 1;
        int r = rs / 3;
        int s = rs - r * 3;
        bf16x8 b0 = bfr[(kk * 8 + nt0    ) * 64 + lane];
        bf16x8 b1 = bfr[(kk * 8 + nt0 + 1) * 64 + lane];
        int abase = (r * LDSW + s) * LDST + (kk & 1) * 32 + laneoff;
        #pragma unroll
        for (int mt = 0; mt < 7; ++mt) {
            bf16x8 a = *(const bf16x8*)&xs[abase + mt * 16 * LDST];
            acc[mt][0] = __builtin_amdgcn_mfma_f32_16x16x32_bf16(a, b0, acc[mt][0], 0, 0, 0);
            acc[mt][1] = __builtin_amdgcn_mfma_f32_16x16x32_bf16(a, b1, acc[mt][1], 0, 0, 0);
        }
    }
    float* orow = out + (size_t)(n * H + h) * (W * CO);
    int colc = wave * 32 + (lane & 15);
    int rowb = (lane >> 4) * 4;
    #pragma unroll
    for (int mt = 0; mt < 7; ++mt)
        #pragma unroll
        for (int t2 = 0; t2 < 2; ++t2)
            #pragma unroll
            for (int rg = 0; rg < 4; ++rg) {
                int m = mt * 16 + rowb + rg;
                orow[m * CO + colc + t2 * 16] =
                    floorf(acc[mt][t2][rg] * 0.0078125f) * 0.0078125f;
            }
}

extern "C" void kernel_launch(void* const* d_in, const int* in_sizes, int n_in,
                              void* d_out, int out_size, void* d_ws, size_t ws_size,
                              hipStream_t stream) {
    const float* x = (const float*)d_in[0];     // (32,112,112,64) fp32 NHWC
    const float* w = (const float*)d_in[1];     // (3,3,64,128) fp32 HWIO
    float* out = (float*)d_out;                 // (32,112,112,128) fp32

    short* bp = (short*)d_ws;                   // 147456 B packed weights
    const size_t BP_BYTES = 147456;
    const size_t XQ_BYTES = (size_t)NIMG * H * W * CI * 2;   // 51,380,224 B
    quant_pack_w<<<288, 256, 0, stream>>>(w, bp);

    if (ws_size >= BP_BYTES + XQ_BYTES) {
        short* xqp = (short*)((char*)d_ws + BP_BYTES);
        quant_x<<<12544, 256, 0, stream>>>(x, xqp);          // 12544*256*8 == 25690112
        conv2<<<NIMG * 56, 256, 0, stream>>>(xqp, bp, out);  // 1792 blocks
    } else {
        conv_fb<<<NIMG * H, 256, 0, stream>>>(x, bp, out);
    }
}